// Round 9
// baseline (144.467 us; speedup 1.0000x reference)
//
#include <hip/hip_runtime.h>
#include <math.h>

// TOF PET forward projection.
// History: R3 97us proj / FETCH 215MB -> R4 Morton sort: FETCH 26MB -> R5
// bucket atomic-storm bug -> R6 4 lanes/LOR: proj 67us -> R7 precomputed
// sorted ray records + 8 lanes/LOR: proj 50us, VGPR=16 (!) -> latency chain:
// one gather in flight per lane. R8: unroll x2 (j, j+8 per iter, stride 16),
// both gathers issued before either use, branchless window weight (w=0
// outside; x+0.0f exact) -> 2x MLP; aux: 16k buckets (scan halved).
// Index-path math is STRICTLY UNFUSED exact-rn f32 (numpy semantics) — DO NOT
// approximate or contract (R0-R2: FMA/ulp deviations => voxel flips =>
// absmax 0.14 > 0.071 threshold). fp contract(off) + plain ops; voxel /3.125
// stays IEEE '/'; /128 as *0.0078125f is bit-identical (power of 2).
// Summation order is free (R4/R5/R6/R7 all at the comparison floor).

#define NB_POS 4096          // 16^3 Morton cells, 25 mm
#define NCLS   4             // window-length classes (32-sample bins)
#define NBUCK  (NB_POS * NCLS)
#define SPL    8             // lanes per LOR

__device__ __forceinline__ int morton4(int x, int y, int z) {
    int m = 0;
#pragma unroll
    for (int b = 0; b < 4; ++b) {
        m |= ((x >> b) & 1) << (3 * b + 0);
        m |= ((y >> b) & 1) << (3 * b + 1);
        m |= ((z >> b) & 1) << (3 * b + 2);
    }
    return m;
}

// Slab clip (strictly unfused, exact rn divs — produces the tmin/tmax the
// reference sees).
__device__ __forceinline__ void slab_clip(
    float p1x, float p1y, float p1z, float dx, float dy, float dz,
    float& tmin, float& tmax)
{
    const float eps = 1e-8f;
    float sdx = (fabsf(dx) < eps) ? eps : dx;
    float sdy = (fabsf(dy) < eps) ? eps : dy;
    float sdz = (fabsf(dz) < eps) ? eps : dz;
    float tax = (-200.f - p1x) / sdx, tbx = (200.f - p1x) / sdx;
    float tay = (-200.f - p1y) / sdy, tby = (200.f - p1y) / sdy;
    float taz = (-200.f - p1z) / sdz, tbz = (200.f - p1z) / sdz;
    tmin = fmaxf(fmaxf(fmaxf(fminf(tax, tbx), fminf(tay, tby)),
                       fminf(taz, tbz)), 0.f);
    tmax = fminf(fminf(fminf(fmaxf(tax, tbx), fmaxf(tay, tby)),
                       fmaxf(taz, tbz)), 1.f);
}

__global__ void bucket_kernel(const float* __restrict__ lors,
                              int* __restrict__ counts,
                              int* __restrict__ tmp, int n) {
#pragma clang fp contract(off)
    int i = blockIdx.x * 256 + threadIdx.x;
    if (i >= n) return;
    const float* lp = lors + (size_t)i * 7;
    float p1x = lp[0], p1y = lp[1], p1z = lp[2];
    float dx = lp[3] - p1x, dy = lp[4] - p1y, dz = lp[5] - p1z;
    float tt = lp[6];
    float L = sqrtf(((dx * dx) + (dy * dy)) + (dz * dz));

    float tmin, tmax;
    slab_clip(p1x, p1y, p1z, dx, dy, dz, tmin, tmax);

    unsigned key;
    if (!(tmax > tmin) || !(L > 0.f)) {
        // Invalids: spread uniformly (kills R5's one-bucket atomic storm).
        key = (unsigned)i & (NBUCK - 1);
    } else {
        float span = tmax - tmin;
        // TOF-center cell (sort key only; approx math OK here)
        float tc = fminf(fmaxf(0.5f + tt / L, tmin), tmax);
        float px = p1x + tc * dx, py = p1y + tc * dy, pz = p1z + tc * dz;
        int cx = (int)fminf(fmaxf((px + 200.f) * 0.04f, 0.f), 15.f);
        int cy = (int)fminf(fmaxf((py + 200.f) * 0.04f, 0.f), 15.f);
        int cz = (int)fminf(fmaxf((pz + 200.f) * 0.04f, 0.f), 15.f);
        // window length -> 2-bit class (32-sample bins): wave-uniform trips
        float jl = ((0.5f + (tt - 90.f) / L) - tmin) / span * 128.f;
        float jh = ((0.5f + (tt + 90.f) / L) - tmin) / span * 128.f;
        jl = fmaxf(jl, 0.f); jh = fminf(jh, 128.f);
        float wlen = fmaxf(jh - jl, 0.f);
        int cls = min(NCLS - 1, (int)(wlen * (1.f / 32.f)));
        key = ((unsigned)morton4(cx, cy, cz) << 2) | (unsigned)cls;
    }
    atomicAdd(&counts[key], 1);
    tmp[i] = (int)key;
}

__global__ void scan_kernel(const int* __restrict__ counts,
                            int* __restrict__ offsets) {
    __shared__ int s[1024];
    int t = threadIdx.x;
    const int PER = NBUCK / 1024;
    int base = t * PER;
    int local[PER];
    int sum = 0;
#pragma unroll
    for (int i = 0; i < PER; ++i) { local[i] = counts[base + i]; sum += local[i]; }
    s[t] = sum;
    __syncthreads();
    for (int off = 1; off < 1024; off <<= 1) {
        int v = (t >= off) ? s[t - off] : 0;
        __syncthreads();
        s[t] += v;
        __syncthreads();
    }
    int excl = (t == 0) ? 0 : s[t - 1];
#pragma unroll
    for (int i = 0; i < PER; ++i) { offsets[base + i] = excl; excl += local[i]; }
}

// Scatter + setup: computes per-LOR ray record once, writes SORTED arrays.
__global__ void scatter_kernel(const float* __restrict__ lors,
                               const int* __restrict__ tmp,
                               int* __restrict__ offsets,
                               float4* __restrict__ recS,   // {tmin,span,L,pack}
                               float4* __restrict__ ls8,    // 2 per LOR
                               int n) {
#pragma clang fp contract(off)
    int i = blockIdx.x * 256 + threadIdx.x;
    if (i >= n) return;
    const float* lp = lors + (size_t)i * 7;
    float p1x = lp[0], p1y = lp[1], p1z = lp[2];
    float p2x = lp[3], p2y = lp[4], p2z = lp[5];
    float tt = lp[6];
    float dx = p2x - p1x, dy = p2y - p1y, dz = p2z - p1z;
    float L = sqrtf(((dx * dx) + (dy * dy)) + (dz * dz));

    float tmin, tmax;
    slab_clip(p1x, p1y, p1z, dx, dy, dz, tmin, tmax);

    float span, recL;
    int jlo, jhi;
    if (!(tmax > tmin) || !(L > 0.f)) {
        // invalid or degenerate (step==0 => out 0 regardless)
        tmin = 0.f; span = 0.f; recL = 0.f; jlo = 0; jhi = -1;
    } else {
        span = tmax - tmin;
        recL = L;
        // Closed-form sample range of TOF window, +-2 slop (validated R4-R7);
        // window is a strict subset of [jlo,jhi]; exact |dev|<=90 test kept
        // in proj -> identical contributing sample set.
        const float tlo = 0.5f + (tt - 90.0f) / L;
        const float thi = 0.5f + (tt + 90.0f) / L;
        float jl = ((tlo - tmin) / span) * 128.0f - 0.5f;
        float jh = ((thi - tmin) / span) * 128.0f - 0.5f;
        jl = fminf(fmaxf(jl - 2.0f, 0.0f), 127.0f);
        jh = fminf(fmaxf(jh + 2.0f, -1.0f), 127.0f);
        jlo = (int)jl;
        jhi = (int)ceilf(jh);
        if (jhi > 127) jhi = 127;
    }

    int slot = atomicAdd(&offsets[tmp[i]], 1);
    int pk = (jlo << 16) | (jhi & 0xFFFF);
    recS[slot] = make_float4(tmin, span, recL, __int_as_float(pk));
    ls8[2 * slot + 0] = make_float4(p1x, p1y, p1z, p2x);
    ls8[2 * slot + 1] = make_float4(p2y, p2z, tt, __int_as_float(i));
}

__global__ __launch_bounds__(256) void proj_kernel(
    const float* __restrict__ image,
    const float4* __restrict__ recS,
    const float4* __restrict__ ls8,
    float* __restrict__ out,
    int n_lors, int chunks)
{
#pragma clang fp contract(off)
    // XCD swizzle: block b -> XCD (b&7) works the (b&7)-th chunk of sorted order
    const int b = blockIdx.x;
    const int sb = (b & 7) * chunks + (b >> 3);
    const int idx = sb * 256 + (int)threadIdx.x;
    const int gid = idx >> 3;          // sorted LOR slot
    const int s   = idx & 7;           // sub-lane 0..7
    if (gid >= n_lors) return;

    const float4 a  = ls8[2 * gid + 0];
    const float4 c  = ls8[2 * gid + 1];
    const float4 r  = recS[gid];
    const float p1x = a.x, p1y = a.y, p1z = a.z;
    const float dx = a.w - p1x, dy = c.x - p1y, dz = c.y - p1z;
    const float ttof = c.z;
    const int   orig = __float_as_int(c.w);
    const float tmin = r.x, span = r.y, L = r.z;
    const int   pk   = __float_as_int(r.w);
    const int   jlo  = pk >> 16;
    const int   jhi  = (int)(short)(pk & 0xFFFF);

    float acc = 0.0f;
    for (int j0 = jlo + s; j0 <= jhi; j0 += 2 * SPL) {
        const int j1 = j0 + SPL;
        const bool a1 = (j1 <= jhi);

        // ---- addresses for BOTH samples first (2 loads in flight) ----
        const float frac0 = ((float)j0 + 0.5f) * 0.0078125f;   // exact
        const float t0 = tmin + (frac0 * span);                 // UNFUSED
        const float px0 = p1x + (t0 * dx);                      // UNFUSED
        const float py0 = p1y + (t0 * dy);
        const float pz0 = p1z + (t0 * dz);
        int vx0 = (int)floorf((px0 + 200.0f) / 3.125f);         // exact rn div
        int vy0 = (int)floorf((py0 + 200.0f) / 3.125f);
        int vz0 = (int)floorf((pz0 + 200.0f) / 3.125f);
        vx0 = min(max(vx0, 0), 127);
        vy0 = min(max(vy0, 0), 127);
        vz0 = min(max(vz0, 0), 127);

        const float frac1 = ((float)j1 + 0.5f) * 0.0078125f;
        const float t1 = tmin + (frac1 * span);
        const float px1 = p1x + (t1 * dx);
        const float py1 = p1y + (t1 * dy);
        const float pz1 = p1z + (t1 * dz);
        int vx1 = (int)floorf((px1 + 200.0f) / 3.125f);
        int vy1 = (int)floorf((py1 + 200.0f) / 3.125f);
        int vz1 = (int)floorf((pz1 + 200.0f) / 3.125f);
        vx1 = min(max(vx1, 0), 127);
        vy1 = min(max(vy1, 0), 127);
        vz1 = min(max(vz1, 0), 127);

        const float v0 = image[(((vx0 << 7) | vy0) << 7) | vz0];
        const float v1 = image[(((vx1 << 7) | vy1) << 7) | vz1];

        // ---- weights (branchless; w=0 outside window; x+0.0f exact) ----
        const float dev0 = ((t0 - 0.5f) * L) - ttof;            // unfused
        const float dev1 = ((t1 - 0.5f) * L) - ttof;
        const float w0 = (fabsf(dev0) <= 90.0f)
                       ? 0.06649038f * __expf((dev0 * dev0) * (-5.5555556e-4f))
                       : 0.0f;
        const float w1 = (a1 && fabsf(dev1) <= 90.0f)
                       ? 0.06649038f * __expf((dev1 * dev1) * (-5.5555556e-4f))
                       : 0.0f;
        acc += v0 * w0;
        acc += v1 * w1;
    }

    // combine 8 sub-lanes (summation order free — validated R4-R7)
    acc += __shfl_xor(acc, 1, 64);
    acc += __shfl_xor(acc, 2, 64);
    acc += __shfl_xor(acc, 4, 64);

    if (s == 0) {
        const float step = (span * L) * 0.0078125f;   // /128 bit-identical
        out[orig] = acc * step;
    }
}

// Fallback (ws too small): self-contained thread-per-LOR, unsorted.
__global__ __launch_bounds__(256) void proj_fallback(
    const float* __restrict__ image,
    const float* __restrict__ lors,
    float* __restrict__ out, int n_lors)
{
#pragma clang fp contract(off)
    const int lor = blockIdx.x * 256 + threadIdx.x;
    if (lor >= n_lors) return;
    const float* lp = lors + (size_t)lor * 7;
    const float p1x = lp[0], p1y = lp[1], p1z = lp[2];
    const float dx = lp[3] - p1x, dy = lp[4] - p1y, dz = lp[5] - p1z;
    const float ttof = lp[6];
    const float L = sqrtf(((dx * dx) + (dy * dy)) + (dz * dz));
    float tmin, tmax;
    slab_clip(p1x, p1y, p1z, dx, dy, dz, tmin, tmax);
    const float span = fmaxf(tmax - tmin, 0.0f);
    if (!(tmax > tmin)) { out[lor] = 0.0f; return; }
    float acc = 0.0f;
    for (int j = 0; j < 128; ++j) {
        const float frac = ((float)j + 0.5f) * 0.0078125f;
        const float t = tmin + (frac * span);
        const float dev = ((t - 0.5f) * L) - ttof;
        if (fabsf(dev) <= 90.0f) {
            const float px = p1x + (t * dx);
            const float py = p1y + (t * dy);
            const float pz = p1z + (t * dz);
            int vx = (int)floorf((px + 200.0f) / 3.125f);
            int vy = (int)floorf((py + 200.0f) / 3.125f);
            int vz = (int)floorf((pz + 200.0f) / 3.125f);
            vx = min(max(vx, 0), 127);
            vy = min(max(vy, 0), 127);
            vz = min(max(vz, 0), 127);
            const float val = image[(((vx << 7) | vy) << 7) | vz];
            const float w = 0.06649038f *
                            __expf((dev * dev) * (-5.5555556e-4f));
            acc += val * w;
        }
    }
    out[lor] = acc * ((span * L) * 0.0078125f);
}

extern "C" void kernel_launch(void* const* d_in, const int* in_sizes, int n_in,
                              void* d_out, int out_size, void* d_ws, size_t ws_size,
                              hipStream_t stream) {
    const float* image = (const float*)d_in[0];   // 128^3 fp32
    const float* lors  = (const float*)d_in[1];   // N x 7 fp32
    float* out = (float*)d_out;                   // N fp32
    const int n = in_sizes[1] / 7;

    // ws layout: counts[NBUCK] | offsets[NBUCK] | tmp[n] | (16B align)
    //            recS[n]x16B | ls8[2n]x16B
    char* base = (char*)d_ws;
    int* counts  = (int*)base;
    int* offsets = counts + NBUCK;
    int* tmp     = offsets + NBUCK;
    size_t off = (size_t)(2 * NBUCK + n) * sizeof(int);
    off = (off + 15) & ~(size_t)15;
    float4* recS = (float4*)(base + off);
    float4* ls8  = (float4*)(base + off + (size_t)n * 16);
    const size_t need = off + (size_t)n * 48;
    const bool do_sort = (ws_size >= need);

    if (do_sort) {
        hipMemsetAsync(counts, 0, NBUCK * sizeof(int), stream);
        bucket_kernel<<<(n + 255) / 256, 256, 0, stream>>>(lors, counts, tmp, n);
        scan_kernel<<<1, 1024, 0, stream>>>(counts, offsets);
        scatter_kernel<<<(n + 255) / 256, 256, 0, stream>>>(lors, tmp, offsets,
                                                            recS, ls8, n);
        const int nthreads = n * SPL;
        const int nblocks = (nthreads + 255) / 256;
        const int nb8 = ((nblocks + 7) / 8) * 8;
        proj_kernel<<<nb8, 256, 0, stream>>>(image, recS, ls8, out, n, nb8 >> 3);
    } else {
        proj_fallback<<<(n + 255) / 256, 256, 0, stream>>>(image, lors, out, n);
    }
}